// Round 1
// baseline (424.693 us; speedup 1.0000x reference)
//
#include <hip/hip_runtime.h>
#include <stdint.h>

// Problem constants (fixed by setup_inputs; all tensors f32)
#define B_ROWS 4096
#define D_IN   784
#define H_DIM  800
#define D_OUT  10
#define T_SIM  32
#define N_ELEM (B_ROWS * D_IN)   // 3211264
#define CAP    448               // spiking-list cap/row (mean ~376, sd ~14)

// ---------------------------------------------------------------------------
// Bit-exact JAX threefry2x32 (key = PRNGKey(42) = {0, 42})
// ---------------------------------------------------------------------------
__device__ __forceinline__ void threefry2x32(uint32_t k0, uint32_t k1,
                                             uint32_t& x0, uint32_t& x1) {
  uint32_t ks0 = k0, ks1 = k1, ks2 = k0 ^ k1 ^ 0x1BD11BDAu;
  x0 += ks0; x1 += ks1;
#define TF_RND(r) { x0 += x1; x1 = (x1 << (r)) | (x1 >> (32 - (r))); x1 ^= x0; }
  TF_RND(13) TF_RND(15) TF_RND(26) TF_RND(6)
  x0 += ks1; x1 += ks2 + 1u;
  TF_RND(17) TF_RND(29) TF_RND(16) TF_RND(24)
  x0 += ks2; x1 += ks0 + 2u;
  TF_RND(13) TF_RND(15) TF_RND(26) TF_RND(6)
  x0 += ks0; x1 += ks1 + 3u;
  TF_RND(17) TF_RND(29) TF_RND(16) TF_RND(24)
  x0 += ks1; x1 += ks2 + 4u;
  TF_RND(13) TF_RND(15) TF_RND(26) TF_RND(6)
  x0 += ks2; x1 += ks0 + 5u;
#undef TF_RND
}

// K0 (R13 verbatim): x_fixed[i] = (u[i] < x[i]) ? 1 : 0.
__global__ __launch_bounds__(256) void gen_xfixed(const float* __restrict__ x,
                                                  float* __restrict__ xf) {
  int i = blockIdx.x * blockDim.x + threadIdx.x;
  if (i >= N_ELEM) return;
  uint32_t c0 = 0u, c1 = (uint32_t)i;
  threefry2x32(0u, 42u, c0, c1);
  uint32_t bits = c0 ^ c1;
  float u = __uint_as_float((bits >> 9) | 0x3F800000u) - 1.0f;
  xf[i] = (u < x[i]) ? 1.0f : 0.0f;
}

// ---------------------------------------------------------------------------
// K1 (R13 GEMM verbatim — measured 131 us) + mask-emitting epilogue.
// Bit-exact f32 ascending-k single-accumulator fma chain; period loop is the
// identical f32 add chain to the reference scan; mask = multiples of p.
// ---------------------------------------------------------------------------
#define BM 64
#define BN 64
#define BK 16

__global__ __launch_bounds__(256) void gemm_masks(const float* __restrict__ xf,
                                                  const float* __restrict__ W1,
                                                  const float* __restrict__ b1,
                                                  uint32_t* __restrict__ mb) {
  __shared__ __align__(16) float As[BK][BM + 4];   // stride 272B (16B mult)
  __shared__ __align__(16) float Bs[BK][BN + 4];
  const int m0 = blockIdx.y * BM;
  const int n0 = blockIdx.x * BN;
  const int t  = threadIdx.x;        // 0..255
  const int tx = t & 15, ty = t >> 4;
  const int sM = t >> 2;             // 0..63 staging row
  const int sK = (t & 3) * 4;        // 0,4,8,12
  const int hB = n0 + sM;
  const bool bOK = (hB < H_DIM);
  const float* aptr = xf + (m0 + sM) * D_IN + sK;
  const float* bptr = W1 + (bOK ? hB : 0) * D_IN + sK;

  float4 a4 = *(const float4*)(aptr);
  float4 b4 = *(const float4*)(bptr);
  if (!bOK) { b4.x = b4.y = b4.z = b4.w = 0.0f; }

  float acc[4][4] = {};
  for (int kt = 0; kt < D_IN; kt += BK) {   // 784 = 49*16, ascending k
    As[sK + 0][sM] = a4.x; As[sK + 1][sM] = a4.y;
    As[sK + 2][sM] = a4.z; As[sK + 3][sM] = a4.w;
    Bs[sK + 0][sM] = b4.x; Bs[sK + 1][sM] = b4.y;
    Bs[sK + 2][sM] = b4.z; Bs[sK + 3][sM] = b4.w;
    __syncthreads();
    if (kt + BK < D_IN) {                   // prefetch next tile
      a4 = *(const float4*)(aptr + kt + BK);
      b4 = *(const float4*)(bptr + kt + BK);
      if (!bOK) { b4.x = b4.y = b4.z = b4.w = 0.0f; }
    }
#pragma unroll
    for (int kk = 0; kk < BK; kk++) {       // strict ascending k, single acc
      float4 av = *(const float4*)&As[kk][ty * 4];   // ds_read_b128
      float4 bv = *(const float4*)&Bs[kk][tx * 4];   // ds_read_b128
      float a[4] = {av.x, av.y, av.z, av.w};
      float b[4] = {bv.x, bv.y, bv.z, bv.w};
#pragma unroll
      for (int mi = 0; mi < 4; mi++)
#pragma unroll
        for (int ni = 0; ni < 4; ni++)
          acc[mi][ni] = __builtin_fmaf(a[mi], b[ni], acc[mi][ni]);
    }
    __syncthreads();
  }
  // Epilogue: + b1 (f32 add like ref), exact f32 IF-period loop, emit mask32
  const int hOut = n0 + tx * 4;              // multiple of 4
  if (hOut < H_DIM) {
    float4 bb = *(const float4*)&b1[hOut];
#pragma unroll
    for (int mi = 0; mi < 4; mi++) {
      int m = m0 + ty * 4 + mi;
      float c4[4] = {acc[mi][0] + bb.x, acc[mi][1] + bb.y,
                     acc[mi][2] + bb.z, acc[mi][3] + bb.w};
      uint32_t mk4[4];
#pragma unroll
      for (int ni = 0; ni < 4; ni++) {
        float c = c4[ni];
        float v = 0.0f;
        int p = 0;
#pragma unroll 1
        for (int s = 1; s <= T_SIM; s++) {
          float h1 = v + c;                   // f32 add, as reference
          if (h1 >= 1.0f) { p = s; break; }
          v = h1;
        }
        uint32_t mk = 0;
        if (p) for (int s = p; s <= T_SIM; s += p) mk |= 1u << (s - 1);
        mk4[ni] = mk;
      }
      *(uint4*)&mb[(size_t)m * H_DIM + hOut] =
          make_uint4(mk4[0], mk4[1], mk4[2], mk4[3]);
    }
  }
}

// ---------------------------------------------------------------------------
// K2: SNN scan — packed-list exec (1 LDS instr / entry / wave).
// 2 rows/block, 320 threads. Phases:
//   build (waves 0-1): ballot-compact {h, mask} per row, ascending h.
//   fill  (all 5 waves): wave j gathers w-pair from GLOBAL W2 (L1/L2-resident,
//         32 KB — no LDS staging of W2 at all) and writes its own per-(j,r)
//         16-B packed list {mask, w2j, w2j+1, 0}.  ~12 iters/wave.
//   exec  : per entry ONE ds_read_b128 (2-distinct broadcast) + ~6 VALU.
// Exactness: per (row,t,o) the ascending-h single-accumulator gated fold —
// never-spiking h skipped (+0 identity), each step +w or +0 (select form;
// pads have mask=0 -> exact +0.0f). Overflow (>CAP) -> gated full scan over
// global W2, same order, same values.
// LDS: lists 71680 + pkS 7168 (+small) ~ 79 KB -> 2 blocks/CU.
// ---------------------------------------------------------------------------
__global__ __launch_bounds__(320) void snn_scan(const uint32_t* __restrict__ mb,
                                                const float* __restrict__ W2,
                                                const float* __restrict__ b2,
                                                float* __restrict__ out) {
  __shared__ __align__(16) uint4 lists[10 * CAP];     // [(j*2+r)][i], 71680 B
  __shared__ __align__(16) uint2 pkS[2][CAP];         // {h, mask}, 7168 B
  __shared__ int   lenS[2];
  __shared__ float b2f[D_OUT];
  float* c2s = (float*)&pkS[0][0];            // union: [r][t][o], 2560 B
  const int tid  = threadIdx.x;               // 0..319
  const int row0 = blockIdx.x * 2;

  if (tid < D_OUT) b2f[tid] = b2[tid];

  if (tid < 128) {
    // ---- Build (waves 0-1): ballot-compact mask words, ascending h ----
    const int r = tid >> 6, ln = tid & 63;
    const uint64_t lm = (1ull << ln) - 1ull;
    const uint32_t* mrow = mb + (size_t)(row0 + r) * H_DIM;
    uint32_t mv[13];
#pragma unroll
    for (int ch = 0; ch < 13; ++ch) {         // independent coalesced loads
      int h = ch * 64 + ln;
      mv[ch] = (h < H_DIM) ? mrow[h] : 0u;
    }
    int off = 0;
#pragma unroll
    for (int ch = 0; ch < 13; ++ch) {
      bool g = (mv[ch] != 0u);
      uint64_t bal = __ballot(g);
      int pos = off + __popcll(bal & lm);
      if (g && pos < CAP) {
        uint2 pk; pk.x = (uint32_t)(ch * 64 + ln); pk.y = mv[ch];
        pkS[r][pos] = pk;
      }
      off += __popcll(bal);
    }
    if (off <= CAP) {                         // self-pad to multiple of 64
      int lp = (off + 63) & ~63;              // <= CAP since off <= CAP
      int i = off + ln;
      if (i < lp) { pkS[r][i].x = 0u; pkS[r][i].y = 0u; }
    }
    if (ln == 0) lenS[r] = off;
  }
  __syncthreads();

  const int j = tid >> 6;                     // 0..4 (wave = o-pair)
  const int lane = tid & 63;
  const bool ovf = (lenS[0] > CAP) || (lenS[1] > CAP);

  // ---- Fill: wave j packs its {mask, w2j, w2j+1} list, gathering from
  //      global W2 (L1-resident). Parallel in entry: ~12 iters/wave. ----
  if (!ovf) {
    const float* w2a = W2 + (size_t)(2 * j) * H_DIM;
    const float* w2b = w2a + H_DIM;
#pragma unroll
    for (int r = 0; r < 2; ++r) {
      const int Lp = (lenS[r] + 63) & ~63;    // <= CAP (448 = 7*64)
      uint4* dst = &lists[(j * 2 + r) * CAP];
      for (int i = lane; i < Lp; i += 64) {
        uint2 pk = pkS[r][i];                 // b64 coalesced
        float wx = w2a[pk.x];                 // L1/L2-hit dword gather
        float wy = w2b[pk.x];
        dst[i] = make_uint4(pk.y, __float_as_uint(wx), __float_as_uint(wy), 0u);
      }
    }
  }
  __syncthreads();

  // ---- Exec: wave j = o-pair, lanes (t, r); ONE LDS op per entry ----
  float s0 = 0.0f, s1 = 0.0f;
  const int t = lane & 31;
  const int r = lane >> 5;
  if (!ovf) {
    const int Lpad = (lenS[r] + 63) & ~63;    // per-r trip count (divergent ok)
    const uint4* lp = &lists[(j * 2 + r) * CAP];
#pragma unroll 4
    for (int i = 0; i < Lpad; ++i) {
      uint4 e = lp[i];                        // b128, 2-distinct broadcast
      bool g = (e.x >> t) & 1u;
      s0 += g ? __uint_as_float(e.y) : 0.0f;  // identical op to ref (+w / +0)
      s1 += g ? __uint_as_float(e.z) : 0.0f;
    }
  } else {                                    // overflow fallback: gated scan
    const uint32_t* mrow = mb + (size_t)(row0 + r) * H_DIM;
    const uint32_t vbit = 1u << t;
    const float* w2a = W2 + (size_t)(2 * j) * H_DIM;
    const float* w2b = w2a + H_DIM;
    for (int h = 0; h < H_DIM; ++h) {
      uint32_t mk = mrow[h];
      float wx = w2a[h], wy = w2b[h];         // L1/L2-hit
      s0 += (mk & vbit) ? wx : 0.0f;
      s1 += (mk & vbit) ? wy : 0.0f;
    }
  }
  __syncthreads();                            // all pkS reads complete
  c2s[((r * T_SIM) + t) * D_OUT + 2 * j]     = s0;   // union region write
  c2s[((r * T_SIM) + t) * D_OUT + 2 * j + 1] = s1;
  __syncthreads();

  // ---- Layer-2 IF scan + spike count (exact f32 ref order) ----
  if (tid < 2 * D_OUT) {
    const int rr = tid / D_OUT, o = tid % D_OUT;
    const float bb = b2f[o];
    float v = 0.0f; int cnt = 0;
#pragma unroll
    for (int tt = 0; tt < T_SIM; ++tt) {
      float cur2 = c2s[((rr * T_SIM) + tt) * D_OUT + o] + bb;  // f32 add
      float h2 = v + cur2;                    // f32 add
      bool spk = (h2 >= 1.0f);
      cnt += spk ? 1 : 0;
      v = spk ? 0.0f : h2;
    }
    out[(size_t)(row0 + rr) * D_OUT + o] = (float)cnt;
  }
}

// ---------------------------------------------------------------------------
extern "C" void kernel_launch(void* const* d_in, const int* in_sizes, int n_in,
                              void* d_out, int out_size, void* d_ws, size_t ws_size,
                              hipStream_t stream) {
  const float* x  = (const float*)d_in[0];
  const float* W1 = (const float*)d_in[1];
  const float* b1 = (const float*)d_in[2];
  const float* W2 = (const float*)d_in[3];
  const float* b2 = (const float*)d_in[4];
  float* outp = (float*)d_out;

  float*    xf = (float*)d_ws;                      // N_ELEM f32 (12.85 MB)
  uint32_t* mbuf = (uint32_t*)(xf + N_ELEM);        // B*H u32   (13.1 MB)

  gen_xfixed<<<N_ELEM / 256, 256, 0, stream>>>(x, xf);

  dim3 g1((H_DIM + BN - 1) / BN, B_ROWS / BM);      // 13 x 64 = 832 blocks
  gemm_masks<<<g1, 256, 0, stream>>>(xf, W1, b1, mbuf);

  snn_scan<<<B_ROWS / 2, 320, 0, stream>>>(mbuf, W2, b2, outp);
}

// Round 2
// 317.682 us; speedup vs baseline: 1.3369x; 1.3369x over previous
//
#include <hip/hip_runtime.h>
#include <stdint.h>

// Problem constants (fixed by setup_inputs; all tensors f32)
#define B_ROWS 4096
#define D_IN   784
#define H_DIM  800
#define D_OUT  10
#define T_SIM  32
#define N_ELEM (B_ROWS * D_IN)   // 3211264
#define CAP    448               // spiking-list cap/row (mean ~376, sd ~14)

// ---------------------------------------------------------------------------
// Bit-exact JAX threefry2x32 (key = PRNGKey(42) = {0, 42})
// ---------------------------------------------------------------------------
__device__ __forceinline__ void threefry2x32(uint32_t k0, uint32_t k1,
                                             uint32_t& x0, uint32_t& x1) {
  uint32_t ks0 = k0, ks1 = k1, ks2 = k0 ^ k1 ^ 0x1BD11BDAu;
  x0 += ks0; x1 += ks1;
#define TF_RND(r) { x0 += x1; x1 = (x1 << (r)) | (x1 >> (32 - (r))); x1 ^= x0; }
  TF_RND(13) TF_RND(15) TF_RND(26) TF_RND(6)
  x0 += ks1; x1 += ks2 + 1u;
  TF_RND(17) TF_RND(29) TF_RND(16) TF_RND(24)
  x0 += ks2; x1 += ks0 + 2u;
  TF_RND(13) TF_RND(15) TF_RND(26) TF_RND(6)
  x0 += ks0; x1 += ks1 + 3u;
  TF_RND(17) TF_RND(29) TF_RND(16) TF_RND(24)
  x0 += ks1; x1 += ks2 + 4u;
  TF_RND(13) TF_RND(15) TF_RND(26) TF_RND(6)
  x0 += ks2; x1 += ks0 + 5u;
#undef TF_RND
}

// K0 (R13 verbatim): x_fixed[i] = (u[i] < x[i]) ? 1 : 0.
__global__ __launch_bounds__(256) void gen_xfixed(const float* __restrict__ x,
                                                  float* __restrict__ xf) {
  int i = blockIdx.x * blockDim.x + threadIdx.x;
  if (i >= N_ELEM) return;
  uint32_t c0 = 0u, c1 = (uint32_t)i;
  threefry2x32(0u, 42u, c0, c1);
  uint32_t bits = c0 ^ c1;
  float u = __uint_as_float((bits >> 9) | 0x3F800000u) - 1.0f;
  xf[i] = (u < x[i]) ? 1.0f : 0.0f;
}

// ---------------------------------------------------------------------------
// K1: GEMM + mask epilogue. R2 change: 128x64 tile, 8x4 per-thread acc
// (was 64x64 / 4x4).  Per kk: 3 ds_read_b128 (36 cyc) feed 32 fmas (64 cyc)
// -> LDS:VALU 0.56 (was 0.75); LDS read bytes per fma halved.
// Exactness unchanged: each output is a single f32 accumulator with a strict
// ascending-k fma chain; epilogue identical (f32 +b1, f32 IF-period loop).
// LDS 12.8 KB, ~85 VGPR -> ~6 resident blocks/CU.
// ---------------------------------------------------------------------------
#define BM 128
#define BN 64
#define BK 16

__global__ __launch_bounds__(256) void gemm_masks(const float* __restrict__ xf,
                                                  const float* __restrict__ W1,
                                                  const float* __restrict__ b1,
                                                  uint32_t* __restrict__ mb) {
  __shared__ __align__(16) float As[BK][BM + 4];   // 16 x 132 (stride 528 B, 16B mult)
  __shared__ __align__(16) float Bs[BK][BN + 4];   // 16 x 68  (stride 272 B, 16B mult)
  const int m0 = blockIdx.y * BM;
  const int n0 = blockIdx.x * BN;
  const int t  = threadIdx.x;        // 0..255
  const int tx = t & 15;             // n-group: 4 cols each (0..60)
  const int ty = t >> 4;             // m-group: 8 rows each (0..120)
  const int sM = t >> 2;             // 0..63 staging row
  const int sK = (t & 3) * 4;        // 0,4,8,12
  const int hB = n0 + sM;
  const bool bOK = (hB < H_DIM);
  const float* aptr0 = xf + (size_t)(m0 + sM) * D_IN + sK;        // rows 0..63
  const float* aptr1 = xf + (size_t)(m0 + 64 + sM) * D_IN + sK;   // rows 64..127
  const float* bptr  = W1 + (size_t)(bOK ? hB : 0) * D_IN + sK;

  float4 a4a = *(const float4*)(aptr0);
  float4 a4b = *(const float4*)(aptr1);
  float4 b4  = *(const float4*)(bptr);
  if (!bOK) { b4.x = b4.y = b4.z = b4.w = 0.0f; }

  float acc[8][4] = {};
  for (int kt = 0; kt < D_IN; kt += BK) {   // 784 = 49*16, ascending k
    As[sK + 0][sM] = a4a.x; As[sK + 1][sM] = a4a.y;
    As[sK + 2][sM] = a4a.z; As[sK + 3][sM] = a4a.w;
    As[sK + 0][64 + sM] = a4b.x; As[sK + 1][64 + sM] = a4b.y;
    As[sK + 2][64 + sM] = a4b.z; As[sK + 3][64 + sM] = a4b.w;
    Bs[sK + 0][sM] = b4.x; Bs[sK + 1][sM] = b4.y;
    Bs[sK + 2][sM] = b4.z; Bs[sK + 3][sM] = b4.w;
    __syncthreads();
    if (kt + BK < D_IN) {                   // prefetch next tile
      a4a = *(const float4*)(aptr0 + kt + BK);
      a4b = *(const float4*)(aptr1 + kt + BK);
      b4  = *(const float4*)(bptr + kt + BK);
      if (!bOK) { b4.x = b4.y = b4.z = b4.w = 0.0f; }
    }
#pragma unroll
    for (int kk = 0; kk < BK; kk++) {       // strict ascending k, single acc
      float4 av0 = *(const float4*)&As[kk][ty * 8];       // ds_read_b128
      float4 av1 = *(const float4*)&As[kk][ty * 8 + 4];   // ds_read_b128
      float4 bv  = *(const float4*)&Bs[kk][tx * 4];       // ds_read_b128
      float a[8] = {av0.x, av0.y, av0.z, av0.w, av1.x, av1.y, av1.z, av1.w};
      float b[4] = {bv.x, bv.y, bv.z, bv.w};
#pragma unroll
      for (int mi = 0; mi < 8; mi++)
#pragma unroll
        for (int ni = 0; ni < 4; ni++)
          acc[mi][ni] = __builtin_fmaf(a[mi], b[ni], acc[mi][ni]);
    }
    __syncthreads();
  }
  // Epilogue: + b1 (f32 add like ref), exact f32 IF-period loop, emit mask32
  const int hOut = n0 + tx * 4;              // multiple of 4
  if (hOut < H_DIM) {
    float4 bb = *(const float4*)&b1[hOut];
#pragma unroll
    for (int mi = 0; mi < 8; mi++) {
      int m = m0 + ty * 8 + mi;
      float c4[4] = {acc[mi][0] + bb.x, acc[mi][1] + bb.y,
                     acc[mi][2] + bb.z, acc[mi][3] + bb.w};
      uint32_t mk4[4];
#pragma unroll
      for (int ni = 0; ni < 4; ni++) {
        float c = c4[ni];
        float v = 0.0f;
        int p = 0;
#pragma unroll 1
        for (int s = 1; s <= T_SIM; s++) {
          float h1 = v + c;                   // f32 add, as reference
          if (h1 >= 1.0f) { p = s; break; }
          v = h1;
        }
        uint32_t mk = 0;
        if (p) for (int s = p; s <= T_SIM; s += p) mk |= 1u << (s - 1);
        mk4[ni] = mk;
      }
      *(uint4*)&mb[(size_t)m * H_DIM + hOut] =
          make_uint4(mk4[0], mk4[1], mk4[2], mk4[3]);
    }
  }
}

// ---------------------------------------------------------------------------
// K2: SNN scan — REVERTED to the proven 40 KB / 4-blocks-per-CU version
// (prior session ~145 us).  R1's 79 KB packed-list variant collapsed
// occupancy to 1 block/CU (14.4% occ, 225 us) -> latency-bound.  Here:
// LDS = W2T 32000 + pkS 7168 (+small) < 40960 -> 4 blocks/CU (20 waves).
// Exec per entry: 1 b64 pk read + 1 b64 w read (both <=2-distinct,
// conflict-free) + ~4 VALU; LDS-pipe-throughput-bound at ~97 us model.
// Exactness: per (row,t,o) ascending-h single-accumulator gated fold —
// never-spiking h skipped (+0 identity), each step +w or +0 (select form;
// pads have mask=0). Overflow (>CAP) -> gated full scan, same order.
// ---------------------------------------------------------------------------
__global__ __launch_bounds__(320) void snn_scan(const uint32_t* __restrict__ mb,
                                                const float* __restrict__ W2,
                                                const float* __restrict__ b2,
                                                float* __restrict__ out) {
  __shared__ __align__(16) float W2T[H_DIM * D_OUT];  // [h][o], 32000 B
  __shared__ __align__(16) uint2 pkS[2][CAP];         // {h*40, mask}, 7168 B
  __shared__ int   lenS[2];
  __shared__ float b2f[D_OUT];
  float* c2s = (float*)&pkS[0][0];            // union: [r][t][o], 2560 B
  const int tid  = threadIdx.x;               // 0..319
  const int row0 = blockIdx.x * 2;

  if (tid < D_OUT) b2f[tid] = b2[tid];

  if (tid < 128) {
    // ---- Build (waves 0-1): ballot-compact mask words, ascending h ----
    const int r = tid >> 6, ln = tid & 63;
    const uint64_t lm = (1ull << ln) - 1ull;
    const uint32_t* mrow = mb + (size_t)(row0 + r) * H_DIM;
    uint32_t mv[13];
#pragma unroll
    for (int ch = 0; ch < 13; ++ch) {         // independent coalesced loads
      int h = ch * 64 + ln;
      mv[ch] = (h < H_DIM) ? mrow[h] : 0u;
    }
    int off = 0;
#pragma unroll
    for (int ch = 0; ch < 13; ++ch) {
      bool g = (mv[ch] != 0u);
      uint64_t bal = __ballot(g);
      int pos = off + __popcll(bal & lm);
      if (g && pos < CAP) {
        uint2 pk; pk.x = (uint32_t)((ch * 64 + ln) * 40); pk.y = mv[ch];
        pkS[r][pos] = pk;
      }
      off += __popcll(bal);
    }
    if (off <= CAP) {                         // self-pad to multiple of 64
      int lp = (off + 63) & ~63;              // <= CAP since off <= CAP
      int i = off + ln;
      if (i < lp) { pkS[r][i].x = 0u; pkS[r][i].y = 0u; }
    }
    if (ln == 0) lenS[r] = off;
  } else {
    // ---- W2T staging (waves 2-4): coalesced read, LDS scatter ----
    for (int e = tid - 128; e < H_DIM * D_OUT; e += 192) {
      int o = e / H_DIM, h = e - o * H_DIM;
      W2T[h * D_OUT + o] = W2[e];
    }
  }
  __syncthreads();

  // ---- Exec: wave j = o-pair, lanes (t, r); 2 LDS ops per entry ----
  float s0 = 0.0f, s1 = 0.0f;
  const int j = tid >> 6;                     // 0..4
  const int lane = tid & 63;
  const int t = lane & 31;
  const int r = lane >> 5;
  const bool ovf = (lenS[0] > CAP) || (lenS[1] > CAP);
  {
    if (!ovf) {
      const int Lpad = (lenS[r] + 63) & ~63;  // per-r trip count (divergent ok)
      const uint2* pp = pkS[r];
      const char* wbase = (const char*)W2T + 8 * j;
#pragma unroll 4
      for (int i = 0; i < Lpad; ++i) {
        uint2 pk = pp[i];                     // b64, 2-distinct broadcast
        float2 w = *(const float2*)(wbase + pk.x);  // b64, 2-distinct
        bool g = (pk.y >> t) & 1u;
        s0 += g ? w.x : 0.0f;                 // identical op to ref (+w / +0)
        s1 += g ? w.y : 0.0f;
      }
    } else {                                  // overflow fallback: gated scan
      const uint32_t* mrow = mb + (size_t)(row0 + r) * H_DIM;
      const uint32_t vbit = 1u << t;
      for (int h = 0; h < H_DIM; ++h) {
        uint32_t mk = mrow[h];
        float2 w = *(const float2*)&W2T[h * D_OUT + 2 * j];
        s0 += (mk & vbit) ? w.x : 0.0f;
        s1 += (mk & vbit) ? w.y : 0.0f;
      }
    }
  }
  __syncthreads();                            // all pk reads complete
  c2s[((r * T_SIM) + t) * D_OUT + 2 * j]     = s0;   // union region write
  c2s[((r * T_SIM) + t) * D_OUT + 2 * j + 1] = s1;
  __syncthreads();

  // ---- Layer-2 IF scan + spike count (exact f32 ref order) ----
  if (tid < 2 * D_OUT) {
    const int rr = tid / D_OUT, o = tid % D_OUT;
    const float bb = b2f[o];
    float v = 0.0f; int cnt = 0;
#pragma unroll
    for (int tt = 0; tt < T_SIM; ++tt) {
      float cur2 = c2s[((rr * T_SIM) + tt) * D_OUT + o] + bb;  // f32 add
      float h2 = v + cur2;                    // f32 add
      bool spk = (h2 >= 1.0f);
      cnt += spk ? 1 : 0;
      v = spk ? 0.0f : h2;
    }
    out[(size_t)(row0 + rr) * D_OUT + o] = (float)cnt;
  }
}

// ---------------------------------------------------------------------------
extern "C" void kernel_launch(void* const* d_in, const int* in_sizes, int n_in,
                              void* d_out, int out_size, void* d_ws, size_t ws_size,
                              hipStream_t stream) {
  const float* x  = (const float*)d_in[0];
  const float* W1 = (const float*)d_in[1];
  const float* b1 = (const float*)d_in[2];
  const float* W2 = (const float*)d_in[3];
  const float* b2 = (const float*)d_in[4];
  float* outp = (float*)d_out;

  float*    xf = (float*)d_ws;                      // N_ELEM f32 (12.85 MB)
  uint32_t* mbuf = (uint32_t*)(xf + N_ELEM);        // B*H u32   (13.1 MB)

  gen_xfixed<<<N_ELEM / 256, 256, 0, stream>>>(x, xf);

  dim3 g1((H_DIM + BN - 1) / BN, B_ROWS / BM);      // 13 x 32 = 416 blocks
  gemm_masks<<<g1, 256, 0, stream>>>(xf, W1, b1, mbuf);

  snn_scan<<<B_ROWS / 2, 320, 0, stream>>>(mbuf, W2, b2, outp);
}